// Round 1
// baseline (657.359 us; speedup 1.0000x reference)
//
#include <hip/hip_runtime.h>

// GraphAttentionLayer fused kernel, f32 baseline.
// Shapes: B=32, T=256, C=64, Fin=Fout=128. 8192 independent (b,t) tiles.
// Per tile: h = x@W ; src/dst = h@attn ; e=leaky(src_i+dst_j); softmax_j;
//           out = alpha@h ; LayerNorm over F ; relu.

constexpr int   NTILES    = 32 * 256;   // B*T
constexpr float NEG_SLOPE = 0.2f;
constexpr float LN_EPS    = 1e-5f;
#define NTHREADS 512

__launch_bounds__(NTHREADS, 1)
__global__ void gat_fused(const float* __restrict__ x,
                          const float* __restrict__ W,
                          const float* __restrict__ a_src,
                          const float* __restrict__ a_dst,
                          const float* __restrict__ gamma,
                          const float* __restrict__ beta,
                          float* __restrict__ out)
{
    __shared__ float sW[128][128];   // 64 KB, loaded once per block
    __shared__ float sx[64][132];    // 33 KB, holds x tile then h tile (pad 132 for bank spread)
    __shared__ float s_src[64];
    __shared__ float s_dst[64];
    __shared__ float s_as[128], s_ad[128], s_g[128], s_b[128];

    const int t = threadIdx.x;

    // ---- one-time staging: W, attn vectors, gamma/beta ----
    {
        const float4* W4  = reinterpret_cast<const float4*>(W);
        float4*       sW4 = reinterpret_cast<float4*>(&sW[0][0]);
        #pragma unroll
        for (int c = 0; c < 8; ++c)
            sW4[t + NTHREADS * c] = W4[t + NTHREADS * c];
        if (t < 128) {
            s_as[t] = a_src[t];
            s_ad[t] = a_dst[t];
            s_g[t]  = gamma[t];
            s_b[t]  = beta[t];
        }
    }

    const int ti  = t >> 5;   // 0..15  (GEMM1 row quad)
    const int tj  = t & 31;   // 0..31  (GEMM1 col quad)
    const int i   = t >> 3;   // 0..63  (row for softmax/GEMM2/LN)
    const int g   = t & 7;    // 0..7   (16-feature slice)
    const int rot = g >> 1;   // j-stagger to avoid LDS bank conflicts in GEMM2

    for (int tile = blockIdx.x; tile < NTILES; tile += gridDim.x) {
        const float* xb = x   + (size_t)tile * (64 * 128);
        float*       ob = out + (size_t)tile * (64 * 128);

        __syncthreads();   // previous tile fully consumed (also covers W staging, iter 0)

        // ---- stage x tile (coalesced float4) ----
        {
            const float4* x4 = reinterpret_cast<const float4*>(xb);
            #pragma unroll
            for (int c = 0; c < 4; ++c) {
                int    idx = t + NTHREADS * c;       // 0..2047 float4s
                float4 v   = x4[idx];
                int row = idx >> 5;                  // 32 float4 per row
                int col = (idx & 31) << 2;
                *reinterpret_cast<float4*>(&sx[row][col]) = v;
            }
        }
        __syncthreads();

        // ---- GEMM1: h[4ti+r][4tj+c] = sum_k x[4ti+r][k] * W[k][4tj+c] ----
        float acc[4][4];
        #pragma unroll
        for (int r = 0; r < 4; ++r) {
            acc[r][0] = 0.f; acc[r][1] = 0.f; acc[r][2] = 0.f; acc[r][3] = 0.f;
        }

        #pragma unroll 4
        for (int k4 = 0; k4 < 32; ++k4) {
            const int kb = k4 << 2;
            float4 a0 = *reinterpret_cast<const float4*>(&sx[(ti << 2) + 0][kb]);
            float4 a1 = *reinterpret_cast<const float4*>(&sx[(ti << 2) + 1][kb]);
            float4 a2 = *reinterpret_cast<const float4*>(&sx[(ti << 2) + 2][kb]);
            float4 a3 = *reinterpret_cast<const float4*>(&sx[(ti << 2) + 3][kb]);
            float4 b0 = *reinterpret_cast<const float4*>(&sW[kb + 0][tj << 2]);
            float4 b1 = *reinterpret_cast<const float4*>(&sW[kb + 1][tj << 2]);
            float4 b2 = *reinterpret_cast<const float4*>(&sW[kb + 2][tj << 2]);
            float4 b3 = *reinterpret_cast<const float4*>(&sW[kb + 3][tj << 2]);
            #pragma unroll
            for (int r = 0; r < 4; ++r) {
                float4 a = (r == 0) ? a0 : (r == 1) ? a1 : (r == 2) ? a2 : a3;
                acc[r][0] += a.x * b0.x + a.y * b1.x + a.z * b2.x + a.w * b3.x;
                acc[r][1] += a.x * b0.y + a.y * b1.y + a.z * b2.y + a.w * b3.y;
                acc[r][2] += a.x * b0.z + a.y * b1.z + a.z * b2.z + a.w * b3.z;
                acc[r][3] += a.x * b0.w + a.y * b1.w + a.z * b2.w + a.w * b3.w;
            }
        }
        __syncthreads();   // everyone done reading sx as x

        // ---- write h over the x buffer ----
        #pragma unroll
        for (int r = 0; r < 4; ++r) {
            float4 v;
            v.x = acc[r][0]; v.y = acc[r][1]; v.z = acc[r][2]; v.w = acc[r][3];
            *reinterpret_cast<float4*>(&sx[(ti << 2) + r][tj << 2]) = v;
        }
        __syncthreads();

        // ---- src/dst scores: per-row dot(h[i,:], attn) via 8-lane groups ----
        {
            float ps = 0.f, pd = 0.f;
            #pragma unroll
            for (int s = 0; s < 16; ++s) {
                int   f  = g + (s << 3);
                float hv = sx[i][f];
                ps += hv * s_as[f];
                pd += hv * s_ad[f];
            }
            #pragma unroll
            for (int msk = 1; msk < 8; msk <<= 1) {
                ps += __shfl_xor(ps, msk, 64);
                pd += __shfl_xor(pd, msk, 64);
            }
            if (g == 0) { s_src[i] = ps; s_dst[i] = pd; }
        }
        __syncthreads();

        // ---- softmax over j + GEMM2 + LayerNorm + relu ----
        {
            const float srci = s_src[i];

            // pass 1: row max of leaky(src_i + dst_j)
            float m = -1e30f;
            #pragma unroll 8
            for (int j = 0; j < 64; ++j) {
                float e = srci + s_dst[j];
                e = (e >= 0.f) ? e : NEG_SLOPE * e;
                m = fmaxf(m, e);
            }

            // pass 2: accumulate out[i][16g..16g+15] and denom
            float4 o0 = {0,0,0,0}, o1 = {0,0,0,0}, o2 = {0,0,0,0}, o3 = {0,0,0,0};
            float  denom = 0.f;
            const int fbase = g << 4;
            #pragma unroll 4
            for (int jj = 0; jj < 64; ++jj) {
                int   j = (jj + rot) & 63;           // lane stagger: bank-conflict-free
                float e = srci + s_dst[j];
                e = (e >= 0.f) ? e : NEG_SLOPE * e;
                float w = __expf(e - m);
                denom += w;
                const float* hr = &sx[j][fbase];
                float4 h0 = *reinterpret_cast<const float4*>(hr + 0);
                float4 h1 = *reinterpret_cast<const float4*>(hr + 4);
                float4 h2 = *reinterpret_cast<const float4*>(hr + 8);
                float4 h3 = *reinterpret_cast<const float4*>(hr + 12);
                o0.x += w * h0.x; o0.y += w * h0.y; o0.z += w * h0.z; o0.w += w * h0.w;
                o1.x += w * h1.x; o1.y += w * h1.y; o1.z += w * h1.z; o1.w += w * h1.w;
                o2.x += w * h2.x; o2.y += w * h2.y; o2.z += w * h2.z; o2.w += w * h2.w;
                o3.x += w * h3.x; o3.y += w * h3.y; o3.z += w * h3.z; o3.w += w * h3.w;
            }

            const float inv = 1.0f / denom;
            o0.x *= inv; o0.y *= inv; o0.z *= inv; o0.w *= inv;
            o1.x *= inv; o1.y *= inv; o1.z *= inv; o1.w *= inv;
            o2.x *= inv; o2.y *= inv; o2.z *= inv; o2.w *= inv;
            o3.x *= inv; o3.y *= inv; o3.z *= inv; o3.w *= inv;

            // LN stats over the 128-feature row: 8-lane shuffle reduction
            float s  = o0.x + o0.y + o0.z + o0.w + o1.x + o1.y + o1.z + o1.w
                     + o2.x + o2.y + o2.z + o2.w + o3.x + o3.y + o3.z + o3.w;
            float ss = o0.x*o0.x + o0.y*o0.y + o0.z*o0.z + o0.w*o0.w
                     + o1.x*o1.x + o1.y*o1.y + o1.z*o1.z + o1.w*o1.w
                     + o2.x*o2.x + o2.y*o2.y + o2.z*o2.z + o2.w*o2.w
                     + o3.x*o3.x + o3.y*o3.y + o3.z*o3.z + o3.w*o3.w;
            #pragma unroll
            for (int msk = 1; msk < 8; msk <<= 1) {
                s  += __shfl_xor(s,  msk, 64);
                ss += __shfl_xor(ss, msk, 64);
            }
            const float mu   = s * (1.f / 128.f);
            const float var  = ss * (1.f / 128.f) - mu * mu;
            const float rstd = rsqrtf(var + LN_EPS);

            float* op = ob + (i << 7) + fbase;
            float4 v;
            v.x = fmaxf((o0.x - mu) * rstd * s_g[fbase +  0] + s_b[fbase +  0], 0.f);
            v.y = fmaxf((o0.y - mu) * rstd * s_g[fbase +  1] + s_b[fbase +  1], 0.f);
            v.z = fmaxf((o0.z - mu) * rstd * s_g[fbase +  2] + s_b[fbase +  2], 0.f);
            v.w = fmaxf((o0.w - mu) * rstd * s_g[fbase +  3] + s_b[fbase +  3], 0.f);
            *reinterpret_cast<float4*>(op + 0) = v;
            v.x = fmaxf((o1.x - mu) * rstd * s_g[fbase +  4] + s_b[fbase +  4], 0.f);
            v.y = fmaxf((o1.y - mu) * rstd * s_g[fbase +  5] + s_b[fbase +  5], 0.f);
            v.z = fmaxf((o1.z - mu) * rstd * s_g[fbase +  6] + s_b[fbase +  6], 0.f);
            v.w = fmaxf((o1.w - mu) * rstd * s_g[fbase +  7] + s_b[fbase +  7], 0.f);
            *reinterpret_cast<float4*>(op + 4) = v;
            v.x = fmaxf((o2.x - mu) * rstd * s_g[fbase +  8] + s_b[fbase +  8], 0.f);
            v.y = fmaxf((o2.y - mu) * rstd * s_g[fbase +  9] + s_b[fbase +  9], 0.f);
            v.z = fmaxf((o2.z - mu) * rstd * s_g[fbase + 10] + s_b[fbase + 10], 0.f);
            v.w = fmaxf((o2.w - mu) * rstd * s_g[fbase + 11] + s_b[fbase + 11], 0.f);
            *reinterpret_cast<float4*>(op + 8) = v;
            v.x = fmaxf((o3.x - mu) * rstd * s_g[fbase + 12] + s_b[fbase + 12], 0.f);
            v.y = fmaxf((o3.y - mu) * rstd * s_g[fbase + 13] + s_b[fbase + 13], 0.f);
            v.z = fmaxf((o3.z - mu) * rstd * s_g[fbase + 14] + s_b[fbase + 14], 0.f);
            v.w = fmaxf((o3.w - mu) * rstd * s_g[fbase + 15] + s_b[fbase + 15], 0.f);
            *reinterpret_cast<float4*>(op + 12) = v;
        }
    }
}

extern "C" void kernel_launch(void* const* d_in, const int* in_sizes, int n_in,
                              void* d_out, int out_size, void* d_ws, size_t ws_size,
                              hipStream_t stream) {
    const float* x   = (const float*)d_in[0];
    const float* W   = (const float*)d_in[1];
    const float* asv = (const float*)d_in[2];
    const float* adv = (const float*)d_in[3];
    const float* gm  = (const float*)d_in[4];
    const float* bt  = (const float*)d_in[5];
    float* out = (float*)d_out;

    hipLaunchKernelGGL(gat_fused, dim3(2048), dim3(NTHREADS), 0, stream,
                       x, W, asv, adv, gm, bt, out);
}

// Round 2
// 119.086 us; speedup vs baseline: 5.5200x; 5.5200x over previous
//
#include <hip/hip_runtime.h>

// GAT fused, bf16-MFMA version.
// Per (b,t) tile: h = x@W (MFMA) ; src/dst scores ; softmax(leaky(src_i+dst_j)) ;
// out^T = h^T @ alpha^T (MFMA, transposed so LN + stores are wave-local) ; LN ; relu.

typedef __attribute__((ext_vector_type(8))) short short8;  // 8 bf16 (4 VGPR)
typedef __attribute__((ext_vector_type(4))) float f32x4;

constexpr int   NTILES    = 8192;     // B*T
constexpr float NEG_SLOPE = 0.2f;
constexpr float LN_EPS    = 1e-5f;

__device__ __forceinline__ unsigned short f2bf(float f) {
    unsigned int u = __builtin_bit_cast(unsigned int, f);
    return (unsigned short)((u + 0x7FFFu + ((u >> 16) & 1u)) >> 16);
}
__device__ __forceinline__ float bf2f(unsigned short h) {
    unsigned int u = (unsigned int)h << 16;
    return __builtin_bit_cast(float, u);
}
// XOR-swizzled byte offsets (T2): spread row-strided accesses across banks.
__device__ __forceinline__ unsigned swz256(int row, int bytecol) {  // 256 B rows
    return (unsigned)(row * 256 + bytecol) ^ (unsigned)((row & 7) << 4);
}
__device__ __forceinline__ unsigned swz128(int row, int bytecol) {  // 128 B rows
    return (unsigned)(row * 128 + bytecol) ^ (unsigned)((row & 7) << 4);
}

__launch_bounds__(256, 2)
__global__ void gat_mfma(const float* __restrict__ x,
                         const float* __restrict__ W,
                         const float* __restrict__ a_src,
                         const float* __restrict__ a_dst,
                         const float* __restrict__ gamma,
                         const float* __restrict__ beta,
                         float* __restrict__ out)
{
    __shared__ unsigned short sWt[128 * 128]; // W^T: sWt[n][k]=W[k][n], bf16, swz256
    __shared__ unsigned short sX [64 * 128];  // x tile [m][k] bf16, swz256
    __shared__ unsigned short sHt[128 * 64];  // h^T [n][j] bf16, swz128
    __shared__ unsigned short sP [64 * 64];   // alpha [i][j] bf16, swz128
    __shared__ float s_as[128], s_ad[128], s_g[128], s_b[128];
    __shared__ float s_pS[4][64], s_pD[4][64];
    __shared__ float s_src[64], s_dst[64];

    const int t    = threadIdx.x;
    const int lane = t & 63;
    const int w    = t >> 6;      // wave 0..3
    const int l15  = lane & 15;
    const int lg   = lane >> 4;   // 0..3

    // ---- one-time: stage W^T as bf16 (scalar transpose writes), vectors ----
    {
        const float4* W4 = reinterpret_cast<const float4*>(W);
        for (int c = 0; c < 16; ++c) {
            int idx4 = t + 256 * c;          // 0..4095
            float4 v = W4[idx4];
            int k  = idx4 >> 5;              // 32 float4 per 128-wide row
            int n0 = (idx4 & 31) << 2;
            *(unsigned short*)((char*)sWt + swz256(n0 + 0, k * 2)) = f2bf(v.x);
            *(unsigned short*)((char*)sWt + swz256(n0 + 1, k * 2)) = f2bf(v.y);
            *(unsigned short*)((char*)sWt + swz256(n0 + 2, k * 2)) = f2bf(v.z);
            *(unsigned short*)((char*)sWt + swz256(n0 + 3, k * 2)) = f2bf(v.w);
        }
        if (t < 128) {
            s_as[t] = a_src[t]; s_ad[t] = a_dst[t];
            s_g[t]  = gamma[t]; s_b[t]  = beta[t];
        }
    }

    for (int tile = blockIdx.x; tile < NTILES; tile += gridDim.x) {
        const float* xb = x   + (size_t)tile * 8192;
        float*       ob = out + (size_t)tile * 8192;

        // ---- stage x -> bf16 LDS (8 f32 chunks, one b128 write each) ----
        {
            const float4* x4 = reinterpret_cast<const float4*>(xb);
            #pragma unroll
            for (int c = 0; c < 4; ++c) {
                int idx8 = t + 256 * c;        // chunk of 8 f32, 0..1023
                float4 v0 = x4[idx8 * 2];
                float4 v1 = x4[idx8 * 2 + 1];
                int m  = idx8 >> 4;            // 16 chunks per row
                int k0 = (idx8 & 15) << 3;
                uint4 pk;
                pk.x = (unsigned)f2bf(v0.x) | ((unsigned)f2bf(v0.y) << 16);
                pk.y = (unsigned)f2bf(v0.z) | ((unsigned)f2bf(v0.w) << 16);
                pk.z = (unsigned)f2bf(v1.x) | ((unsigned)f2bf(v1.y) << 16);
                pk.w = (unsigned)f2bf(v1.z) | ((unsigned)f2bf(v1.w) << 16);
                *(uint4*)((char*)sX + swz256(m, k0 * 2)) = pk;
            }
        }
        __syncthreads();   // (1) x (and W, first iter) staged

        // ---- GEMM1: h = x @ W. Wave w owns cols [32w, 32w+32). ----
        f32x4 acc[4][2];
        #pragma unroll
        for (int mi = 0; mi < 4; ++mi) {
            acc[mi][0] = f32x4{0.f, 0.f, 0.f, 0.f};
            acc[mi][1] = f32x4{0.f, 0.f, 0.f, 0.f};
        }
        #pragma unroll
        for (int kb = 0; kb < 4; ++kb) {
            const int kbyte = (kb * 32 + lg * 8) * 2;
            short8 bfr0 = *(const short8*)((char*)sWt + swz256(32 * w +  0 + l15, kbyte));
            short8 bfr1 = *(const short8*)((char*)sWt + swz256(32 * w + 16 + l15, kbyte));
            #pragma unroll
            for (int mi = 0; mi < 4; ++mi) {
                short8 afr = *(const short8*)((char*)sX + swz256(mi * 16 + l15, kbyte));
                acc[mi][0] = __builtin_amdgcn_mfma_f32_16x16x32_bf16(afr, bfr0, acc[mi][0], 0, 0, 0);
                acc[mi][1] = __builtin_amdgcn_mfma_f32_16x16x32_bf16(afr, bfr1, acc[mi][1], 0, 0, 0);
            }
        }

        // ---- h -> sHt (h^T[n][j], bf16). Lane holds rows m0..m0+3, col n. ----
        #pragma unroll
        for (int mi = 0; mi < 4; ++mi) {
            const int m0 = mi * 16 + lg * 4;
            #pragma unroll
            for (int nb = 0; nb < 2; ++nb) {
                const int n = 32 * w + nb * 16 + l15;
                uint2 pk;
                pk.x = (unsigned)f2bf(acc[mi][nb][0]) | ((unsigned)f2bf(acc[mi][nb][1]) << 16);
                pk.y = (unsigned)f2bf(acc[mi][nb][2]) | ((unsigned)f2bf(acc[mi][nb][3]) << 16);
                *(uint2*)((char*)sHt + swz128(n, m0 * 2)) = pk;
            }
        }
        __syncthreads();   // (2) h complete

        // ---- src/dst scores: thread (p = t>>6, i = t&63) does 32-feature slice ----
        {
            const int i = t & 63, p = t >> 6;
            float ps = 0.f, pd = 0.f;
            #pragma unroll 8
            for (int q = 0; q < 32; ++q) {
                const int n = 32 * p + q;
                float hv = bf2f(*(const unsigned short*)((char*)sHt + swz128(n, i * 2)));
                ps = fmaf(hv, s_as[n], ps);
                pd = fmaf(hv, s_ad[n], pd);
            }
            s_pS[p][i] = ps; s_pD[p][i] = pd;
        }
        __syncthreads();   // (3)
        if (t < 64) {
            s_src[t] = s_pS[0][t] + s_pS[1][t] + s_pS[2][t] + s_pS[3][t];
            s_dst[t] = s_pD[0][t] + s_pD[1][t] + s_pD[2][t] + s_pD[3][t];
        }
        __syncthreads();   // (4)

        // ---- alpha: thread (i = t>>2, jg = t&3) does 16 of row i ----
        {
            const int i = t >> 2, jg = t & 3;
            const float srci = s_src[i];
            float e[16];
            float mx = -1e30f;
            #pragma unroll
            for (int q = 0; q < 16; ++q) {
                float v = srci + s_dst[jg * 16 + q];
                v = (v >= 0.f) ? v : NEG_SLOPE * v;
                e[q] = v;
                mx = fmaxf(mx, v);
            }
            mx = fmaxf(mx, __shfl_xor(mx, 1, 64));
            mx = fmaxf(mx, __shfl_xor(mx, 2, 64));
            float sm = 0.f;
            #pragma unroll
            for (int q = 0; q < 16; ++q) { e[q] = __expf(e[q] - mx); sm += e[q]; }
            sm += __shfl_xor(sm, 1, 64);
            sm += __shfl_xor(sm, 2, 64);
            const float inv = 1.0f / sm;
            unsigned short a_[16];
            #pragma unroll
            for (int q = 0; q < 16; ++q) a_[q] = f2bf(e[q] * inv);
            uint4 pk0, pk1;
            pk0.x = (unsigned)a_[0]  | ((unsigned)a_[1]  << 16);
            pk0.y = (unsigned)a_[2]  | ((unsigned)a_[3]  << 16);
            pk0.z = (unsigned)a_[4]  | ((unsigned)a_[5]  << 16);
            pk0.w = (unsigned)a_[6]  | ((unsigned)a_[7]  << 16);
            pk1.x = (unsigned)a_[8]  | ((unsigned)a_[9]  << 16);
            pk1.y = (unsigned)a_[10] | ((unsigned)a_[11] << 16);
            pk1.z = (unsigned)a_[12] | ((unsigned)a_[13] << 16);
            pk1.w = (unsigned)a_[14] | ((unsigned)a_[15] << 16);
            *(uint4*)((char*)sP + swz128(i, jg * 32))      = pk0;
            *(uint4*)((char*)sP + swz128(i, jg * 32 + 16)) = pk1;
        }
        __syncthreads();   // (5) alpha ready

        // ---- GEMM2 (transposed): out^T[n][m] = sum_j hT[n][j] * alpha[m][j].
        //      Wave w owns m-cols [16w, 16w+16); full n per wave -> LN is local.
        f32x4 o[8];
        #pragma unroll
        for (int mi = 0; mi < 8; ++mi) o[mi] = f32x4{0.f, 0.f, 0.f, 0.f};
        #pragma unroll
        for (int kb = 0; kb < 2; ++kb) {
            const int jbyte = (kb * 32 + lg * 8) * 2;
            short8 bfr = *(const short8*)((char*)sP + swz128(w * 16 + l15, jbyte));
            #pragma unroll
            for (int mi = 0; mi < 8; ++mi) {
                short8 afr = *(const short8*)((char*)sHt + swz128(mi * 16 + l15, jbyte));
                o[mi] = __builtin_amdgcn_mfma_f32_16x16x32_bf16(afr, bfr, o[mi], 0, 0, 0);
            }
        }

        // ---- LayerNorm over n (features): lane group {l, l^16, l^32} covers all 128 ----
        float sm1 = 0.f, sm2 = 0.f;
        #pragma unroll
        for (int mi = 0; mi < 8; ++mi)
            #pragma unroll
            for (int r = 0; r < 4; ++r) { float v = o[mi][r]; sm1 += v; sm2 += v * v; }
        sm1 += __shfl_xor(sm1, 16, 64); sm2 += __shfl_xor(sm2, 16, 64);
        sm1 += __shfl_xor(sm1, 32, 64); sm2 += __shfl_xor(sm2, 32, 64);
        const float mu   = sm1 * (1.f / 128.f);
        const float var  = sm2 * (1.f / 128.f) - mu * mu;
        const float rstd = rsqrtf(var + LN_EPS);

        float* orow = ob + (w * 16 + l15) * 128;
        #pragma unroll
        for (int mi = 0; mi < 8; ++mi) {
            const int n0 = mi * 16 + lg * 4;
            float4 gv = *(const float4*)&s_g[n0];
            float4 bv = *(const float4*)&s_b[n0];
            float4 vo;
            vo.x = fmaxf((o[mi][0] - mu) * rstd * gv.x + bv.x, 0.f);
            vo.y = fmaxf((o[mi][1] - mu) * rstd * gv.y + bv.y, 0.f);
            vo.z = fmaxf((o[mi][2] - mu) * rstd * gv.z + bv.z, 0.f);
            vo.w = fmaxf((o[mi][3] - mu) * rstd * gv.w + bv.w, 0.f);
            *(float4*)(orow + n0) = vo;
        }
    }
}

extern "C" void kernel_launch(void* const* d_in, const int* in_sizes, int n_in,
                              void* d_out, int out_size, void* d_ws, size_t ws_size,
                              hipStream_t stream) {
    const float* x   = (const float*)d_in[0];
    const float* W   = (const float*)d_in[1];
    const float* asv = (const float*)d_in[2];
    const float* adv = (const float*)d_in[3];
    const float* gm  = (const float*)d_in[4];
    const float* bt  = (const float*)d_in[5];
    float* out = (float*)d_out;

    hipLaunchKernelGGL(gat_mfma, dim3(512), dim3(256), 0, stream,
                       x, W, asv, adv, gm, bt, out);
}